// Round 4
// baseline (8522.695 us; speedup 1.0000x reference)
//
#include <hip/hip_runtime.h>
#include <cmath>

#define RN 512
#define RT 1024
#define RB 64

typedef float f32x2 __attribute__((ext_vector_type(2)));

// tanh(x) = 1 - 2/(e^{2x}+1); __expf -> v_mul + v_exp_f32 (~3 VALU ops).
// abs error ~1e-7; saturates correctly to +/-1 at large |x|.
__device__ __forceinline__ float fast_tanh(float x) {
    float e = __expf(2.0f * x);
    return 1.0f - 2.0f / (e + 1.0f);
}

// dual-fp32 packed FMA: acc.{x,y} += w.{x,y} * r.{x,y}
#define PKFMA(acc, wpair, rx, ry) { f32x2 rp = { (rx), (ry) }; \
    asm("v_pk_fma_f32 %0, %1, %2, %0" : "+v"(acc) : "v"(wpair), "v"(rp)); }

// 256 blocks x 512 threads (1/CU). Block = (row-part p in [0,8), pair-group g
// in [0,32)) handling batches b0=g, b1=g+32 with ONE shared W pass per step.
// W slice (64 rows x 512) lives in LDS as packed bf16 pairs (exactly 64 KB),
// XOR-quad-swizzled so ds_read_b128 is conflict-free per octet phase.
// Lane mapping: wave wv owns rows wv*8..wv*8+7; r=lane&7 row, c=lane>>3 is the
// 64-wide k-chunk. Dot reduce = shfl_xor over lane bits 3..5. h is replicated
// across the 8 c-lanes (no divergence); c==0 stores. Cross-block exchange via
// outH rows (unique address per step) + one per-pair monotonic atomic counter
// (8 arrivals/step), agent-scope release/acquire.
__global__ void __launch_bounds__(512, 2) rnn_step_kernel(
    const float* __restrict__ h0,
    const float* __restrict__ X,
    const float* __restrict__ W,
    const float* __restrict__ tanh0,
    float* __restrict__ outH,
    unsigned int* __restrict__ ctr)
{
    const int bid = blockIdx.x;
    const int xcd = bid & 7;
    const int s   = bid >> 3;          // 0..31
    const int pairIdx = s >> 3;        // 0..3
    const int part    = s & 7;         // 0..7
    const int g  = xcd * 4 + pairIdx;  // 0..31
    const int b0 = g, b1 = g + 32;

    const int tid  = threadIdx.x;
    const int wv   = tid >> 6;
    const int lane = tid & 63;
    const int r    = lane & 7;
    const int c    = lane >> 3;
    const int rl   = wv * 8 + r;       // row_local 0..63
    const int grow = part * 64 + rl;   // global row 0..511

    __shared__ unsigned int Wl[64][256];   // 64 KB exactly

    // ---- one-time stage: W slice -> LDS as bf16 pairs (RNE), quad-swizzled ----
    for (int it = 0; it < 32; ++it) {
        int idx = it * 512 + tid;          // 0..16383
        int row = idx >> 8;                // 0..63
        int cu  = idx & 255;               // packed-u32 column
        const float* wp = W + (size_t)(part * 64 + row) * RN + cu * 2;
        unsigned ua = __float_as_uint(wp[0]);
        unsigned ub = __float_as_uint(wp[1]);
        ua = (ua + 0x7fffu + ((ua >> 16) & 1u)) >> 16;   // RNE to bf16
        ub = (ub + 0x7fffu + ((ub >> 16) & 1u)) >> 16;
        unsigned packed = ua | (ub << 16);               // even k low, odd k high
        int q  = cu >> 2;
        int qs = q ^ (row & 7);                          // bank-quad swizzle
        Wl[row][(qs << 2) | (cu & 3)] = packed;
    }
    __syncthreads();

    const float h0v = h0[grow];
    float hA = h0v, hB = h0v;
    const size_t xoA = (size_t)b0 * RT * RN + grow;
    const size_t xoB = (size_t)b1 * RT * RN + grow;
    float xvA = X[xoA], xvB = X[xoB];

    float* outA = outH + (size_t)b0 * RT * RN;
    float* outB = outH + (size_t)b1 * RT * RN;
    unsigned int* myctr = ctr + g * 32;    // one cacheline per pair-group

    #pragma unroll 1
    for (int t = 0; t < RT; ++t) {
        if (t > 0) {
            if (tid == 0) {
                const unsigned target = 8u * (unsigned)t;
                while (__hip_atomic_load(myctr, __ATOMIC_ACQUIRE, __HIP_MEMORY_SCOPE_AGENT) < target)
                    __builtin_amdgcn_s_sleep(1);
            }
            __syncthreads();
            asm volatile("" ::: "memory");   // keep row loads below the gate
        }

        const float* srcA = (t == 0) ? tanh0 : (outA + (size_t)(t - 1) * RN);
        const float* srcB = (t == 0) ? tanh0 : (outB + (size_t)(t - 1) * RN);
        const float4* ra4 = reinterpret_cast<const float4*>(srcA + c * 64);
        const float4* rb4 = reinterpret_cast<const float4*>(srcB + c * 64);

        f32x2 accA = {0.f, 0.f}, accB = {0.f, 0.f};
        #pragma unroll
        for (int j = 0; j < 8; ++j) {
            uint4 wq = *reinterpret_cast<const uint4*>(
                &Wl[rl][((c * 8 + j) ^ (rl & 7)) << 2]);
            float4 a0 = ra4[2 * j], a1 = ra4[2 * j + 1];
            float4 bq0 = rb4[2 * j], bq1 = rb4[2 * j + 1];
            f32x2 w0 = { __uint_as_float(wq.x << 16), __uint_as_float(wq.x & 0xffff0000u) };
            f32x2 w1 = { __uint_as_float(wq.y << 16), __uint_as_float(wq.y & 0xffff0000u) };
            f32x2 w2 = { __uint_as_float(wq.z << 16), __uint_as_float(wq.z & 0xffff0000u) };
            f32x2 w3 = { __uint_as_float(wq.w << 16), __uint_as_float(wq.w & 0xffff0000u) };
            PKFMA(accA, w0, a0.x, a0.y)
            PKFMA(accA, w1, a0.z, a0.w)
            PKFMA(accA, w2, a1.x, a1.y)
            PKFMA(accA, w3, a1.z, a1.w)
            PKFMA(accB, w0, bq0.x, bq0.y)
            PKFMA(accB, w1, bq0.z, bq0.w)
            PKFMA(accB, w2, bq1.x, bq1.y)
            PKFMA(accB, w3, bq1.z, bq1.w)
        }

        float dA = accA.x + accA.y;
        float dB = accB.x + accB.y;
        dA += __shfl_xor(dA, 8);  dB += __shfl_xor(dB, 8);
        dA += __shfl_xor(dA, 16); dB += __shfl_xor(dB, 16);
        dA += __shfl_xor(dA, 32); dB += __shfl_xor(dB, 32);

        hA = 0.9f * hA + 0.1f * (dA + xvA);
        hB = 0.9f * hB + 0.1f * (dB + xvB);
        const float thA = fast_tanh(hA);
        const float thB = fast_tanh(hB);
        if (c == 0) {
            outA[(size_t)t * RN + grow] = thA;
            outB[(size_t)t * RN + grow] = thB;
        }
        if (t + 1 < RT) {   // prefetch next x; latency hides across the barrier
            xvA = X[xoA + (size_t)(t + 1) * RN];
            xvB = X[xoB + (size_t)(t + 1) * RN];
        }

        __syncthreads();    // each wave drains vmcnt before s_barrier -> stores in L2
        if (tid == 0)
            __hip_atomic_fetch_add(myctr, 1u, __ATOMIC_RELEASE, __HIP_MEMORY_SCOPE_AGENT);
    }
}

// geometry epilogue: geo[b,t,:] = hidden[b,t,:] @ Gw^T + Gb ; one wave per (b,t)
__global__ void geom_kernel(const float* __restrict__ hid,
                            const float* __restrict__ Gw,
                            const float* __restrict__ Gb,
                            float* __restrict__ geo)
{
    const int wid  = (blockIdx.x * blockDim.x + threadIdx.x) >> 6;
    const int lane = threadIdx.x & 63;
    if (wid >= RB * RT) return;
    const float* rowp = hid + (size_t)wid * RN;
    float g0 = 0.f, g1 = 0.f;
    #pragma unroll
    for (int j = 0; j < 8; ++j) {
        float v = rowp[lane + 64 * j];
        g0 = fmaf(v, Gw[lane + 64 * j], g0);
        g1 = fmaf(v, Gw[RN + lane + 64 * j], g1);
    }
    #pragma unroll
    for (int m = 32; m >= 1; m >>= 1) {
        g0 += __shfl_xor(g0, m);
        g1 += __shfl_xor(g1, m);
    }
    if (lane == 0) {
        geo[(size_t)wid * 2]     = g0 + Gb[0];
        geo[(size_t)wid * 2 + 1] = g1 + Gb[1];
    }
}

// per-launch init: tanh(h0) table + zeroed counters (ws poisoned once -> must
// re-init every call; deterministic)
__global__ void init_misc(const float* __restrict__ h0,
                          float* __restrict__ tanh0,
                          unsigned int* __restrict__ ctr)
{
    int i = blockIdx.x * blockDim.x + threadIdx.x;
    if (i < RN) tanh0[i] = tanhf(h0[i]);
    if (i < 32 * 32) ctr[i] = 0u;
}

extern "C" void kernel_launch(void* const* d_in, const int* in_sizes, int n_in,
                              void* d_out, int out_size, void* d_ws, size_t ws_size,
                              hipStream_t stream)
{
    const float* h0 = (const float*)d_in[0];
    const float* X  = (const float*)d_in[1];
    const float* W  = (const float*)d_in[2];
    const float* Gw = (const float*)d_in[3];
    const float* Gb = (const float*)d_in[4];

    float* outH = (float*)d_out;
    float* geo  = outH + (size_t)RB * RT * RN;

    float* tanh0 = (float*)d_ws;                    // 512 floats
    unsigned int* ctr = (unsigned int*)d_ws + RN;   // 32*32 uints

    init_misc<<<4, 512, 0, stream>>>(h0, tanh0, ctr);

    void* kargs[] = { (void*)&h0, (void*)&X, (void*)&W, (void*)&tanh0,
                      (void*)&outH, (void*)&ctr };
    hipLaunchCooperativeKernel(rnn_step_kernel, dim3(256), dim3(512), kargs, 0, stream);

    geom_kernel<<<(RB * RT * 64 + 255) / 256, 256, 0, stream>>>(outH, Gw, Gb, geo);
}

// Round 5
// 5416.199 us; speedup vs baseline: 1.5736x; 1.5736x over previous
//
#include <hip/hip_runtime.h>
#include <hip/hip_fp16.h>
#include <cmath>

#define RN 512
#define RT 1024
#define RB 64

typedef _Float16 half2v __attribute__((ext_vector_type(2)));

__device__ __forceinline__ float fast_tanh(float x) {
    float e = __expf(2.0f * x);           // v_mul + v_exp
    return 1.0f - 2.0f / (e + 1.0f);      // exact saturation at large |x|
}

__device__ __forceinline__ unsigned pack2(float a, float b) {
    unsigned ua = __half_as_ushort(__float2half(a));   // RNE
    unsigned ub = __half_as_ushort(__float2half(b));
    return ua | (ub << 16);
}

__device__ __forceinline__ float dot2(unsigned wa, unsigned tb, float acc) {
#if __has_builtin(__builtin_amdgcn_fdot2)
    half2v a = __builtin_bit_cast(half2v, wa);
    half2v b = __builtin_bit_cast(half2v, tb);
    return __builtin_amdgcn_fdot2(a, b, acc, false);
#else
    asm("v_dot2_f32_f16 %0, %1, %2, %0" : "+v"(acc) : "v"(wa), "v"(tb));
    return acc;
#endif
}

// entry-index -> conflict-free LDS slot (bank-quad = jj ^ c3 per octet phase)
__device__ __forceinline__ int swz(int e) {
    return (e & ~7) | ((e ^ (e >> 3)) & 7);
}

// One block per batch: 64 blocks x 1024 threads, one CU each. Zero cross-block
// sync. W streamed from L2 as f16 pairs in Wpk (exact per-wave access order:
// Wpk[j*1024 + tid], j = r*8+jj) -> perfectly coalesced dwordx4 loads, 512 KB
// per XCD stays L2-hot. tanh(h_t) lives in a 2 KB double-buffered, XOR-swizzled
// LDS buffer of packed f16 pairs. Thread (q=tid>>3, c3=tid&7) owns rows
// 4q..4q+3 x k-chunk [c3*64, +64): 128 v_dot2 per step; reduce over the c3
// octet via shfl_xor(1,2,4); h-update/tanh replicated across the octet
// (branch-free), c3==0 lane stores.
__global__ void __launch_bounds__(1024, 4) rnn_step_kernel(
    const float* __restrict__ h0,
    const float* __restrict__ X,
    const uint4* __restrict__ Wpk,
    float* __restrict__ outH)
{
    const int b    = blockIdx.x;
    const int tid  = threadIdx.x;
    const int c3   = tid & 7;
    const int q    = tid >> 3;          // 0..127
    const int row0 = q * 4;

    __shared__ uint4 tanh_pk[2][64];    // [buf][entry]: entry e = rows 8e..8e+7

    const float* Xrow = X + (size_t)b * RT * RN + row0;
    float* outBase    = outH + (size_t)b * RT * RN + row0;

    // ---- prologue: h = h0, stage tanh(h0) into buf 0 ----
    float4 hv = *reinterpret_cast<const float4*>(h0 + row0);
    float h0r = hv.x, h1r = hv.y, h2r = hv.z, h3r = hv.w;
    {
        float t0 = tanhf(h0r), t1 = tanhf(h1r), t2 = tanhf(h2r), t3 = tanhf(h3r);
        if (c3 == 0) {
            unsigned u0 = pack2(t0, t1), u1 = pack2(t2, t3);
            int e = q >> 1;
            unsigned* p = reinterpret_cast<unsigned*>(&tanh_pk[0][swz(e)]) + (q & 1) * 2;
            *reinterpret_cast<uint2*>(p) = make_uint2(u0, u1);
        }
    }
    float4 xv = *reinterpret_cast<const float4*>(Xrow);   // x_0
    __syncthreads();

    #pragma unroll 1
    for (int t = 0; t < RT; ++t) {
        const int tb = t & 1;

        // tanh(h_t) k-chunk [c3*64, +64) -> 8 swizzled uint4 (conflict-free)
        uint4 t4[8];
        #pragma unroll
        for (int jj = 0; jj < 8; ++jj)
            t4[jj] = tanh_pk[tb][swz(c3 * 8 + jj)];

        // prefetch next x early; latency hides under the dot loop
        const int tn = (t + 1 < RT) ? t + 1 : t;
        float4 xn = *reinterpret_cast<const float4*>(Xrow + (size_t)tn * RN);

        float a0 = 0.f, a1 = 0.f, a2 = 0.f, a3 = 0.f;
        const uint4* wp = Wpk + tid;
        #pragma unroll
        for (int jj = 0; jj < 8; ++jj) {
            uint4 w0 = wp[(0 * 8 + jj) * 1024];
            uint4 w1 = wp[(1 * 8 + jj) * 1024];
            uint4 w2 = wp[(2 * 8 + jj) * 1024];
            uint4 w3 = wp[(3 * 8 + jj) * 1024];
            uint4 tv = t4[jj];
            a0 = dot2(w0.x, tv.x, a0); a0 = dot2(w0.y, tv.y, a0);
            a0 = dot2(w0.z, tv.z, a0); a0 = dot2(w0.w, tv.w, a0);
            a1 = dot2(w1.x, tv.x, a1); a1 = dot2(w1.y, tv.y, a1);
            a1 = dot2(w1.z, tv.z, a1); a1 = dot2(w1.w, tv.w, a1);
            a2 = dot2(w2.x, tv.x, a2); a2 = dot2(w2.y, tv.y, a2);
            a2 = dot2(w2.z, tv.z, a2); a2 = dot2(w2.w, tv.w, a2);
            a3 = dot2(w3.x, tv.x, a3); a3 = dot2(w3.y, tv.y, a3);
            a3 = dot2(w3.z, tv.z, a3); a3 = dot2(w3.w, tv.w, a3);
        }

        // reduce over the 8 c3-lanes (xor stays inside the octet)
        a0 += __shfl_xor(a0, 1); a0 += __shfl_xor(a0, 2); a0 += __shfl_xor(a0, 4);
        a1 += __shfl_xor(a1, 1); a1 += __shfl_xor(a1, 2); a1 += __shfl_xor(a1, 4);
        a2 += __shfl_xor(a2, 1); a2 += __shfl_xor(a2, 2); a2 += __shfl_xor(a2, 4);
        a3 += __shfl_xor(a3, 1); a3 += __shfl_xor(a3, 2); a3 += __shfl_xor(a3, 4);

        // h update + tanh, replicated across the octet (no divergence)
        h0r = 0.9f * h0r + 0.1f * (a0 + xv.x);
        h1r = 0.9f * h1r + 0.1f * (a1 + xv.y);
        h2r = 0.9f * h2r + 0.1f * (a2 + xv.z);
        h3r = 0.9f * h3r + 0.1f * (a3 + xv.w);
        const float t0 = fast_tanh(h0r), t1 = fast_tanh(h1r);
        const float t2 = fast_tanh(h2r), t3 = fast_tanh(h3r);

        if (c3 == 0) {
            *reinterpret_cast<float4*>(outBase + (size_t)t * RN) =
                make_float4(t0, t1, t2, t3);
            unsigned u0 = pack2(t0, t1), u1 = pack2(t2, t3);
            int e = q >> 1;
            unsigned* p = reinterpret_cast<unsigned*>(&tanh_pk[tb ^ 1][swz(e)]) + (q & 1) * 2;
            *reinterpret_cast<uint2*>(p) = make_uint2(u0, u1);
        }
        xv = xn;
        __syncthreads();   // buf tb^1 complete; buf tb reads all done
    }
}

// one-time per launch: repack W into f16-pair tiles in the exact per-wave
// access order Wpk[(r*8+jj)*1024 + tid], tid=(q,c3): rows 4q+r, k = c3*64+jj*8
__global__ void pack_w(const float* __restrict__ W, uint4* __restrict__ Wpk)
{
    int o = blockIdx.x * blockDim.x + threadIdx.x;
    if (o >= 32 * 1024) return;
    int j   = o >> 10;          // 0..31
    int t1k = o & 1023;
    int q   = t1k >> 3;
    int c3  = t1k & 7;
    int r   = j >> 3;
    int jj  = j & 7;
    int row = q * 4 + r;
    int kb  = c3 * 64 + jj * 8;
    const float* src = W + (size_t)row * RN + kb;
    uint4 out;
    out.x = pack2(src[0], src[1]);
    out.y = pack2(src[2], src[3]);
    out.z = pack2(src[4], src[5]);
    out.w = pack2(src[6], src[7]);
    Wpk[o] = out;
}

// geometry epilogue: geo[b,t,:] = hidden[b,t,:] @ Gw^T + Gb ; one wave per (b,t)
__global__ void geom_kernel(const float* __restrict__ hid,
                            const float* __restrict__ Gw,
                            const float* __restrict__ Gb,
                            float* __restrict__ geo)
{
    const int wid  = (blockIdx.x * blockDim.x + threadIdx.x) >> 6;
    const int lane = threadIdx.x & 63;
    if (wid >= RB * RT) return;
    const float* rowp = hid + (size_t)wid * RN;
    float g0 = 0.f, g1 = 0.f;
    #pragma unroll
    for (int j = 0; j < 8; ++j) {
        float v = rowp[lane + 64 * j];
        g0 = fmaf(v, Gw[lane + 64 * j], g0);
        g1 = fmaf(v, Gw[RN + lane + 64 * j], g1);
    }
    #pragma unroll
    for (int m = 32; m >= 1; m >>= 1) {
        g0 += __shfl_xor(g0, m);
        g1 += __shfl_xor(g1, m);
    }
    if (lane == 0) {
        geo[(size_t)wid * 2]     = g0 + Gb[0];
        geo[(size_t)wid * 2 + 1] = g1 + Gb[1];
    }
}

extern "C" void kernel_launch(void* const* d_in, const int* in_sizes, int n_in,
                              void* d_out, int out_size, void* d_ws, size_t ws_size,
                              hipStream_t stream)
{
    const float* h0 = (const float*)d_in[0];
    const float* X  = (const float*)d_in[1];
    const float* W  = (const float*)d_in[2];
    const float* Gw = (const float*)d_in[3];
    const float* Gb = (const float*)d_in[4];

    float* outH = (float*)d_out;
    float* geo  = outH + (size_t)RB * RT * RN;

    uint4* Wpk = (uint4*)d_ws;   // 512 KB

    pack_w<<<128, 256, 0, stream>>>(W, Wpk);
    rnn_step_kernel<<<RB, 1024, 0, stream>>>(h0, X, Wpk, outH);
    geom_kernel<<<(RB * RT * 64 + 255) / 256, 256, 0, stream>>>(outH, Gw, Gb, geo);
}

// Round 6
// 2322.018 us; speedup vs baseline: 3.6704x; 2.3325x over previous
//
#include <hip/hip_runtime.h>
#include <hip/hip_fp16.h>
#include <cmath>

#define RN 512
#define RT 1024
#define RB 64
#define SMEM_BYTES (131072 + 2048 + 16)

typedef _Float16 half2v __attribute__((ext_vector_type(2)));

__device__ __forceinline__ float fast_tanh(float x) {
    float e = __expf(2.0f * x);
    return 1.0f - 2.0f / (e + 1.0f);
}
__device__ __forceinline__ unsigned pack2(float a, float b) {
    return (unsigned)__half_as_ushort(__float2half(a)) |
           ((unsigned)__half_as_ushort(__float2half(b)) << 16);
}
__device__ __forceinline__ float dot2(unsigned wa, unsigned tb, float acc) {
    half2v a = __builtin_bit_cast(half2v, wa);
    half2v b = __builtin_bit_cast(half2v, tb);
    return __builtin_amdgcn_fdot2(a, b, acc, false);
}
// u32-slot swizzles (XOR bits 2..4) -> 2-way-max bank aliasing (free, m136)
__device__ __forceinline__ int swzT(int s)          { return s ^ (((s >> 4) & 7) << 2); }
__device__ __forceinline__ int swzW(int s, int row) { return s ^ ((((s >> 4) ^ (row >> 2)) & 7) << 2); }

// 256 blocks x 512 threads, cooperative, 133 KB dynamic LDS -> exactly 1
// block/CU -> exactly 32 blocks/XCD. Roles assigned by arrival rank WITHIN the
// block's actual XCD (s_getreg HW_REG_XCC_ID) so each batch's 4 blocks are
// guaranteed same-XCD: slot = xcd*32+rank, batch = slot/4, part = slot%4.
// W slice (128 rows x 512, f16-packed, XOR-swizzled) lives entirely in LDS.
// Per-step exchange of tanh(h) goes through outH rows (unique address per t,
// so no stale-L1 hazard) with a per-batch monotonic RELAXED agent atomic
// counter: release ordering comes from __syncthreads' vmcnt drain; acquire
// needs no cache ops because the quad shares one XCD L2 and L1 is
// write-through. Thread (rg=tid>>4, kc=tid&15) owns rows 4rg..4rg+3 x k-chunk
// [kc*32,+32): 64 v_dot2/step, reduce over the 16 kc-lanes, kc==0 updates h.
__global__ void __launch_bounds__(512, 2) rnn_step_kernel(
    const float* __restrict__ h0,
    const float* __restrict__ X,
    const float* __restrict__ W,
    float* __restrict__ outH,
    unsigned* __restrict__ ctr,
    unsigned* __restrict__ xcdctr)
{
    extern __shared__ unsigned char smem[];
    unsigned* Wl  = (unsigned*)smem;               // 128 rows * 256 u32 = 128 KB
    unsigned* tp0 = (unsigned*)(smem + 131072);    // 256 u32 (1 KB)
    unsigned* tp1 = tp0 + 256;                     // 256 u32
    int* bc       = (int*)(tp1 + 256);

    const int tid = threadIdx.x;
    if (tid == 0) {
        unsigned xcd;
        asm volatile("s_getreg_b32 %0, hwreg(HW_REG_XCC_ID)" : "=s"(xcd));
        xcd &= 7u;
        int rank = (int)__hip_atomic_fetch_add(&xcdctr[xcd], 1u,
                        __ATOMIC_RELAXED, __HIP_MEMORY_SCOPE_AGENT);
        int slot = (int)xcd * 32 + rank;
        bc[0] = (slot >> 2) & 63;   // batch
        bc[1] = slot & 3;           // part
    }
    __syncthreads();
    const int batch = bc[0], part = bc[1];
    const int rowbase = part * 128;

    // ---- stage W slice: f32 -> packed f16 pairs, swizzled (one-time) ----
    for (int it = 0; it < 64; ++it) {
        int g   = it * 512 + tid;       // 0..32767 u32-slots
        int row = g >> 8;               // 0..127
        int s   = g & 255;
        float2 wv = *reinterpret_cast<const float2*>(
            W + (size_t)(rowbase + row) * RN + 2 * s);
        Wl[row * 256 + swzW(s, row)] = pack2(wv.x, wv.y);
    }

    const int kc = tid & 15;
    const int rg = tid >> 4;
    const bool owner = (kc == 0);

    // tanh(h0) full row packed into tp0
    if (tid < 256) {
        float2 hv = *reinterpret_cast<const float2*>(h0 + 2 * tid);
        tp0[swzT(tid)] = pack2(tanhf(hv.x), tanhf(hv.y));
    }

    float4 h = {0, 0, 0, 0}, xv = {0, 0, 0, 0};
    const size_t obase = (size_t)batch * RT * RN + rowbase;
    if (owner) {
        h  = *reinterpret_cast<const float4*>(h0 + rowbase + 4 * rg);
        xv = *reinterpret_cast<const float4*>(X + obase + 4 * rg);
    }
    unsigned* myctr = ctr + batch * 32;
    __syncthreads();

    #pragma unroll 1
    for (int t = 0; t < RT; ++t) {
        unsigned* cur = (t & 1) ? tp1 : tp0;
        unsigned* nxt = (t & 1) ? tp0 : tp1;

        const uint4* tc = (const uint4*)cur;
        uint4 tq0 = tc[(kc * 4 + 0) ^ (kc & 7)];
        uint4 tq1 = tc[(kc * 4 + 1) ^ (kc & 7)];
        uint4 tq2 = tc[(kc * 4 + 2) ^ (kc & 7)];
        uint4 tq3 = tc[(kc * 4 + 3) ^ (kc & 7)];

        float acc[4];
        #pragma unroll
        for (int i = 0; i < 4; ++i) {
            const int row = 4 * rg + i;
            const uint4* wb = (const uint4*)(Wl + row * 256);
            const int x7 = (kc ^ (row >> 2)) & 7;
            uint4 w0 = wb[(kc * 4 + 0) ^ x7];
            uint4 w1 = wb[(kc * 4 + 1) ^ x7];
            uint4 w2 = wb[(kc * 4 + 2) ^ x7];
            uint4 w3 = wb[(kc * 4 + 3) ^ x7];
            float a = 0.f;
            a = dot2(w0.x, tq0.x, a); a = dot2(w0.y, tq0.y, a);
            a = dot2(w0.z, tq0.z, a); a = dot2(w0.w, tq0.w, a);
            a = dot2(w1.x, tq1.x, a); a = dot2(w1.y, tq1.y, a);
            a = dot2(w1.z, tq1.z, a); a = dot2(w1.w, tq1.w, a);
            a = dot2(w2.x, tq2.x, a); a = dot2(w2.y, tq2.y, a);
            a = dot2(w2.z, tq2.z, a); a = dot2(w2.w, tq2.w, a);
            a = dot2(w3.x, tq3.x, a); a = dot2(w3.y, tq3.y, a);
            a = dot2(w3.z, tq3.z, a); a = dot2(w3.w, tq3.w, a);
            acc[i] = a;
        }

        #pragma unroll
        for (int m = 1; m <= 8; m <<= 1) {
            acc[0] += __shfl_xor(acc[0], m);
            acc[1] += __shfl_xor(acc[1], m);
            acc[2] += __shfl_xor(acc[2], m);
            acc[3] += __shfl_xor(acc[3], m);
        }

        if (owner) {
            h.x = 0.9f * h.x + 0.1f * (acc[0] + xv.x);
            h.y = 0.9f * h.y + 0.1f * (acc[1] + xv.y);
            h.z = 0.9f * h.z + 0.1f * (acc[2] + xv.z);
            h.w = 0.9f * h.w + 0.1f * (acc[3] + xv.w);
            const float t0 = fast_tanh(h.x), t1 = fast_tanh(h.y);
            const float t2 = fast_tanh(h.z), t3 = fast_tanh(h.w);
            *reinterpret_cast<float4*>(outH + obase + (size_t)t * RN + 4 * rg) =
                make_float4(t0, t1, t2, t3);
            // own band of next-step tanh buffer, written locally (skips L2 trip)
            const int s0 = part * 64 + 2 * rg;
            nxt[swzT(s0)]     = pack2(t0, t1);
            nxt[swzT(s0 + 1)] = pack2(t2, t3);
            const int tn = (t + 1 < RT) ? t + 1 : t;
            xv = *reinterpret_cast<const float4*>(X + obase + (size_t)tn * RN + 4 * rg);
        }

        if (t + 1 < RT) {
            __syncthreads();    // all waves' outH stores drained (vmcnt 0) -> in XCD L2
            if (tid == 0) {
                __hip_atomic_fetch_add(myctr, 1u, __ATOMIC_RELAXED, __HIP_MEMORY_SCOPE_AGENT);
                const unsigned tgt = 4u * (unsigned)(t + 1);
                while (__hip_atomic_load(myctr, __ATOMIC_RELAXED, __HIP_MEMORY_SCOPE_AGENT) < tgt)
                    __builtin_amdgcn_s_sleep(1);
            }
            __syncthreads();    // quad complete: partners' rows visible in L2
            if (tid < 192) {    // pack the 3 partner bands into nxt
                const int pi = tid >> 6;
                const int pp = pi + (pi >= part);
                const int s  = pp * 64 + (tid & 63);
                float2 v = *reinterpret_cast<const float2*>(
                    outH + (size_t)batch * RT * RN + (size_t)t * RN + 2 * s);
                nxt[swzT(s)] = pack2(v.x, v.y);
            }
            __syncthreads();    // nxt complete for step t+1
        }
    }
}

// geometry epilogue: geo[b,t,:] = hidden[b,t,:] @ Gw^T + Gb ; one wave per (b,t)
__global__ void geom_kernel(const float* __restrict__ hid,
                            const float* __restrict__ Gw,
                            const float* __restrict__ Gb,
                            float* __restrict__ geo)
{
    const int wid  = (blockIdx.x * blockDim.x + threadIdx.x) >> 6;
    const int lane = threadIdx.x & 63;
    if (wid >= RB * RT) return;
    const float* rowp = hid + (size_t)wid * RN;
    float g0 = 0.f, g1 = 0.f;
    #pragma unroll
    for (int j = 0; j < 8; ++j) {
        float v = rowp[lane + 64 * j];
        g0 = fmaf(v, Gw[lane + 64 * j], g0);
        g1 = fmaf(v, Gw[RN + lane + 64 * j], g1);
    }
    #pragma unroll
    for (int m = 32; m >= 1; m >>= 1) {
        g0 += __shfl_xor(g0, m);
        g1 += __shfl_xor(g1, m);
    }
    if (lane == 0) {
        geo[(size_t)wid * 2]     = g0 + Gb[0];
        geo[(size_t)wid * 2 + 1] = g1 + Gb[1];
    }
}

// zero barrier + xcd-rank counters every launch (ws poisoned once, never re-poisoned)
__global__ void init_misc(unsigned* __restrict__ ctr, unsigned* __restrict__ xcdctr)
{
    int i = blockIdx.x * blockDim.x + threadIdx.x;
    if (i < RB * 32) ctr[i] = 0u;
    if (i < 8) xcdctr[i] = 0u;
}

extern "C" void kernel_launch(void* const* d_in, const int* in_sizes, int n_in,
                              void* d_out, int out_size, void* d_ws, size_t ws_size,
                              hipStream_t stream)
{
    const float* h0 = (const float*)d_in[0];
    const float* X  = (const float*)d_in[1];
    const float* W  = (const float*)d_in[2];
    const float* Gw = (const float*)d_in[3];
    const float* Gb = (const float*)d_in[4];

    float* outH = (float*)d_out;
    float* geo  = outH + (size_t)RB * RT * RN;

    unsigned* ctr    = (unsigned*)d_ws;            // 64*32
    unsigned* xcdctr = ctr + RB * 32;              // 8

    (void)hipFuncSetAttribute((const void*)rnn_step_kernel,
                              hipFuncAttributeMaxDynamicSharedMemorySize, SMEM_BYTES);

    init_misc<<<4, 512, 0, stream>>>(ctr, xcdctr);

    void* kargs[] = { (void*)&h0, (void*)&X, (void*)&W, (void*)&outH,
                      (void*)&ctr, (void*)&xcdctr };
    hipLaunchCooperativeKernel(rnn_step_kernel, dim3(256), dim3(512),
                               kargs, SMEM_BYTES, stream);

    geom_kernel<<<(RB * RT * 64 + 255) / 256, 256, 0, stream>>>(outH, Gw, Gb, geo);
}